// Round 1
// baseline (147.192 us; speedup 1.0000x reference)
//
#include <hip/hip_runtime.h>
#include <stdint.h>

// out[n,o] = sum_{d,i} q[n,d] x[n,i] W1[d,i,o] + (q @ b1)[n,o]
// GEMM M=4096 N=256 K=16384 (k=d*256+i), fp16 MFMA 32x32x16, fp32 accum.
// A-frag = x-frag * q[row,d] per-lane scalar (v_pk_mul_f16).
// Bias q@b1 folded into split-group 0 as 2 extra K-chunks with A-frag = q-frag.
//
// THIS VERSION: LDS-free main loop. Each wave consumes a DISJOINT 64-col slice
// of every W chunk (no cross-wave reuse), so the previous global_load_lds ->
// ds_read round trip was pure overhead (2.1 GB LDS traffic = 27-41 us floor).
// W and x fragments are loaded straight into VGPRs (Wt/Xt layouts are exactly
// the MFMA fragment layouts), double-buffered in registers with one-chunk
// prefetch. Compiler emits precise counted vmcnt waits for register loads, so
// all manual s_waitcnt/sched_barrier self-sync is gone. LDS=0 + VGPR<=170
// (__launch_bounds__(256,3)) -> 12 waves/CU, all 512 blocks co-resident.
// L2 serves W reuse (64 same-XCD blocks per chunk; sg = bid&7 is XCD-affine).

typedef _Float16 f16;
typedef f16 f16x8 __attribute__((ext_vector_type(8)));
typedef float f32x16 __attribute__((ext_vector_type(16)));

#define NROWS 4096
#define QDIM 64
#define SPLIT 8
#define MBLK 64

// Wt chunk map: sg0 -> chunks 0..63, bias(b1) -> 64,65, sg>=1 -> 66+(sg-1)*64 ...
// chunk layout (16 KB): element ((s*2+h)*256+n)*8+j  <-  B[k = s*16+h*8+j][n]
// prep grid 658: [0,512) W | [512,640) x | [640,656) q->Qt | [656,658) b1
__global__ __launch_bounds__(256) void prep(const float* __restrict__ W,
                                            const float* __restrict__ X,
                                            const float* __restrict__ Q,
                                            const float* __restrict__ B1,
                                            f16* __restrict__ Wt,
                                            f16* __restrict__ Xt,
                                            f16* __restrict__ Qt) {
  const int b = blockIdx.x;
  const int t = threadIdx.x;
  if (b < 512) {
    const int sg = b >> 6, ic = (b >> 3) & 7, dd = b & 7;
    const int g = b + (sg ? 2 : 0);  // skip the 2 bias chunks
    const int k0 = ((sg << 3) + dd) * 256 + (ic << 5);
#pragma unroll
    for (int r = 0; r < 4; ++r) {
      const int gidx = (r << 8) + t;  // (s*2+h)*256 + n
      const int n = gidx & 255;
      const int sh = gidx >> 8;
      f16x8 h;
#pragma unroll
      for (int j = 0; j < 8; ++j)
        h[j] = (f16)W[(size_t)(k0 + (sh << 3) + j) * 256 + n];  // coalesced over n
      *(f16x8*)(Wt + (size_t)g * 8192 + (size_t)gidx * 8) = h;
    }
  } else if (b < 640) {
    // Xt[mb][((hsic)*64+row)*8+j] = x[mb*64+row][hsic*8+j]
    const int bb = b - 512;
    const int mb = bb >> 1, half = bb & 1;
#pragma unroll
    for (int r = 0; r < 4; ++r) {
      const int gidx = (half << 10) + (r << 8) + t;
      const int row = gidx & 63;
      const int hsic = gidx >> 6;
      const float* src = X + (size_t)((mb << 6) + row) * 256 + (hsic << 3);
      float4 a = *(const float4*)src;
      float4 c = *(const float4*)(src + 4);
      f16x8 h;
      h[0] = (f16)a.x; h[1] = (f16)a.y; h[2] = (f16)a.z; h[3] = (f16)a.w;
      h[4] = (f16)c.x; h[5] = (f16)c.y; h[6] = (f16)c.z; h[7] = (f16)c.w;
      *(f16x8*)(Xt + (size_t)mb * 16384 + (size_t)gidx * 8) = h;
    }
  } else if (b < 656) {
    // Qt[mb][(sh*64+row)*8+j] = q[mb*64+row][sh*8+j]  (A-operand layout, 64 k's)
    const int bb = b - 640;  // 0..15, 4 mb each
#pragma unroll
    for (int m = 0; m < 4; ++m) {
      const int mb = (bb << 2) + m;
#pragma unroll
      for (int r = 0; r < 2; ++r) {
        const int u = (r << 8) + t;  // 0..511
        const int row = u & 63;
        const int sh = u >> 6;
        const float* src = Q + (size_t)((mb << 6) + row) * QDIM + (sh << 3);
        float4 a = *(const float4*)src;
        float4 c = *(const float4*)(src + 4);
        f16x8 h;
        h[0] = (f16)a.x; h[1] = (f16)a.y; h[2] = (f16)a.z; h[3] = (f16)a.w;
        h[4] = (f16)c.x; h[5] = (f16)c.y; h[6] = (f16)c.z; h[7] = (f16)c.w;
        *(f16x8*)(Qt + (size_t)mb * 4096 + (size_t)u * 8) = h;
      }
    }
  } else {
    // b1 -> Wt chunks 64,65: B[k=cc*32+sh*8+j][n] = b1[k][n]
    const int cc = b - 656;
#pragma unroll
    for (int r = 0; r < 4; ++r) {
      const int gidx = (r << 8) + t;
      const int n = gidx & 255;
      const int sh = gidx >> 8;
      f16x8 h;
#pragma unroll
      for (int j = 0; j < 8; ++j)
        h[j] = (f16)B1[(size_t)((cc << 5) + (sh << 3) + j) * 256 + n];
      *(f16x8*)(Wt + (size_t)(64 + cc) * 8192 + (size_t)gidx * 8) = h;
    }
  }
}

// Load the wave's 4 W fragments of one chunk straight into registers.
// P already includes the per-lane base wl = hf*4096 + w*1024 + l31*16.
// Frag (s,nt) at +{0,512,8192,8704}  (nt: +512, s: +8192).
#define LOADW(D, P)                          \
  do {                                       \
    D[0] = *(const f16x8*)((P));             \
    D[1] = *(const f16x8*)((P) + 512);       \
    D[2] = *(const f16x8*)((P) + 8192);      \
    D[3] = *(const f16x8*)((P) + 8704);      \
  } while (0)

// Load the wave's 4 x fragments for one ic (index [s*2+mt]).
// xg includes hf*1024 + l31*16; (mt: +512, s: +2048), ic step 4096 B.
#define LOADX(D, IC)                               \
  do {                                             \
    const char* xb_ = xg + ((IC) << 12);           \
    D[0] = *(const f16x8*)(xb_);                   \
    D[1] = *(const f16x8*)(xb_ + 512);             \
    D[2] = *(const f16x8*)(xb_ + 2048);            \
    D[3] = *(const f16x8*)(xb_ + 2560);            \
  } while (0)

// 8 MFMAs for one chunk: A = x-frag * q scalar. XF[s*2+mt], WW[s*2+nt].
#define MFMA8(XF, DD, WW)                                                        \
  do {                                                                           \
    const f16 q0_ = qr[0][DD], q1_ = qr[1][DD];                                  \
    f16x8 a00_ = XF[0] * q0_, a10_ = XF[1] * q1_;                                \
    f16x8 a01_ = XF[2] * q0_, a11_ = XF[3] * q1_;                                \
    acc[0][0] = __builtin_amdgcn_mfma_f32_32x32x16_f16(a00_, WW[0], acc[0][0], 0, 0, 0); \
    acc[1][0] = __builtin_amdgcn_mfma_f32_32x32x16_f16(a10_, WW[0], acc[1][0], 0, 0, 0); \
    acc[0][1] = __builtin_amdgcn_mfma_f32_32x32x16_f16(a00_, WW[1], acc[0][1], 0, 0, 0); \
    acc[1][1] = __builtin_amdgcn_mfma_f32_32x32x16_f16(a10_, WW[1], acc[1][1], 0, 0, 0); \
    acc[0][0] = __builtin_amdgcn_mfma_f32_32x32x16_f16(a01_, WW[2], acc[0][0], 0, 0, 0); \
    acc[1][0] = __builtin_amdgcn_mfma_f32_32x32x16_f16(a11_, WW[2], acc[1][0], 0, 0, 0); \
    acc[0][1] = __builtin_amdgcn_mfma_f32_32x32x16_f16(a01_, WW[3], acc[0][1], 0, 0, 0); \
    acc[1][1] = __builtin_amdgcn_mfma_f32_32x32x16_f16(a11_, WW[3], acc[1][1], 0, 0, 0); \
  } while (0)

// Bias variant: A = q fragment directly (no scalar multiply). QF[s*2+mt].
#define MFMA8Q(QF, WW)                                                           \
  do {                                                                           \
    acc[0][0] = __builtin_amdgcn_mfma_f32_32x32x16_f16(QF[0], WW[0], acc[0][0], 0, 0, 0); \
    acc[1][0] = __builtin_amdgcn_mfma_f32_32x32x16_f16(QF[1], WW[0], acc[1][0], 0, 0, 0); \
    acc[0][1] = __builtin_amdgcn_mfma_f32_32x32x16_f16(QF[0], WW[1], acc[0][1], 0, 0, 0); \
    acc[1][1] = __builtin_amdgcn_mfma_f32_32x32x16_f16(QF[1], WW[1], acc[1][1], 0, 0, 0); \
    acc[0][0] = __builtin_amdgcn_mfma_f32_32x32x16_f16(QF[2], WW[2], acc[0][0], 0, 0, 0); \
    acc[1][0] = __builtin_amdgcn_mfma_f32_32x32x16_f16(QF[3], WW[2], acc[1][0], 0, 0, 0); \
    acc[0][1] = __builtin_amdgcn_mfma_f32_32x32x16_f16(QF[2], WW[3], acc[0][1], 0, 0, 0); \
    acc[1][1] = __builtin_amdgcn_mfma_f32_32x32x16_f16(QF[3], WW[3], acc[1][1], 0, 0, 0); \
  } while (0)

// ---- main GEMM: 512 blocks = 8 split groups (XCD-affine %8) x 64 row-blocks ----
__global__ __launch_bounds__(256, 3) void mlp_main(const float* __restrict__ Q,
                                                   const f16* __restrict__ Wt,
                                                   const f16* __restrict__ Xt,
                                                   const f16* __restrict__ Qt,
                                                   float* __restrict__ out) {
  const int bid = blockIdx.x;
  const int sg = bid & 7;
  const int mb = bid >> 3;
  const int t = threadIdx.x;
  const int w = t >> 6;
  const int l = t & 63;
  const int l31 = l & 31;
  const int hf = l >> 5;

  // W slice base for this sg (+2 skips the bias chunks for sg>=1)
  const char* wg = (const char*)(Wt + (size_t)((sg << 6) + (sg ? 2 : 0)) * 8192);
  const int wl = (hf << 12) + (w << 10) + (l31 << 4);  // per-lane frag base in chunk
  const char* cp = wg + wl;  // walks chunk bases (current chunk lives in WA)

  // per-lane x-frag base for this mb
  const char* xg = (const char*)Xt + ((size_t)mb << 15) + (hf << 10) + (l31 << 4);

  // per-lane q scalars: q[mb*64 + mt*32 + l31][sg*8 + dd]
  f16 qr[2][8];
#pragma unroll
  for (int mt = 0; mt < 2; ++mt) {
    const float* qp = Q + (size_t)((mb << 6) + (mt << 5) + l31) * QDIM + (sg << 3);
#pragma unroll
    for (int dd = 0; dd < 8; ++dd) qr[mt][dd] = (f16)qp[dd];
  }

  f32x16 acc[2][2];
#pragma unroll
  for (int a = 0; a < 2; ++a)
#pragma unroll
    for (int bq = 0; bq < 2; ++bq)
#pragma unroll
      for (int r = 0; r < 16; ++r) acc[a][bq][r] = 0.f;

  // register double buffers (statically indexed: rule-of-thumb #20)
  f16x8 WA[4], WB[4], xfA[4], xfB[4];

  LOADW(WA, cp);   // chunk 0
  LOADX(xfA, 0);   // x frags for ic=0

  // 64 chunks = 8 ic x 8 dd; ic unrolled x2 for xfA/xfB ping-pong,
  // dd unrolled x2 for WA/WB ping-pong. One-chunk register prefetch:
  // loads for chunk c+1 issue before the 8 MFMAs on chunk c.
  for (int ic2 = 0; ic2 < 4; ++ic2) {
    LOADX(xfB, (ic2 << 1) + 1);  // x for odd ic, overlaps this p-loop
#pragma unroll
    for (int p = 0; p < 4; ++p) {
      LOADW(WB, cp + 16384);
      MFMA8(xfA, (p << 1), WA);
      LOADW(WA, cp + 32768);
      MFMA8(xfA, (p << 1) + 1, WB);
      cp += 32768;
    }
    LOADX(xfA, ((ic2 << 1) + 2) & 7);  // x for next even ic (ic2=3: dummy, unused)
#pragma unroll
    for (int p = 0; p < 4; ++p) {
      LOADW(WB, cp + 16384);
      MFMA8(xfB, (p << 1), WA);
      LOADW(WA, cp + 32768);
      MFMA8(xfB, (p << 1) + 1, WB);
      cp += 32768;
    }
  }
  // Loop invariant leaves WA holding chunk 64 (for sg0 that's bias chunk 64;
  // for sg>=1 a stray in-workspace prefetch, discarded).

  // bias tail (sg0 only): 2 extra chunks with A = q-frags from Qt
  if (sg == 0) {
    LOADW(WB, cp + 16384);  // bias chunk 65
    f16x8 QF0[4], QF1[4];
    const char* qg = (const char*)Qt + ((size_t)mb << 13) + (hf << 10) + (l31 << 4);
#pragma unroll
    for (int u = 0; u < 4; ++u)
      QF0[u] = *(const f16x8*)(qg + ((u >> 1) << 11) + ((u & 1) << 9));
#pragma unroll
    for (int u = 0; u < 4; ++u)
      QF1[u] = *(const f16x8*)(qg + 4096 + ((u >> 1) << 11) + ((u & 1) << 9));
    MFMA8Q(QF0, WA);
    MFMA8Q(QF1, WB);
  }

  // epilogue: atomic split-K accumulate onto zero-initialized out.
  // C/D (32x32): col = lane&31, row = (reg&3) + 8*(reg>>2) + 4*(lane>>5)
#pragma unroll
  for (int mt = 0; mt < 2; ++mt) {
#pragma unroll
    for (int nt = 0; nt < 2; ++nt) {
#pragma unroll
      for (int r = 0; r < 16; ++r) {
        const int row = (mb << 6) + (mt << 5) + (r & 3) + ((r >> 2) << 3) + (hf << 2);
        const int col = (w << 6) + (nt << 5) + l31;
        atomicAdd(out + (size_t)row * 256 + col, acc[mt][nt][r]);
      }
    }
  }
}

extern "C" void kernel_launch(void* const* d_in, const int* in_sizes, int n_in,
                              void* d_out, int out_size, void* d_ws, size_t ws_size,
                              hipStream_t stream) {
  (void)in_sizes; (void)n_in; (void)out_size; (void)ws_size;
  const float* x  = (const float*)d_in[0];   // [4096,256]
  const float* q  = (const float*)d_in[1];   // [4096,64]
  const float* W1 = (const float*)d_in[2];   // [64,256,256]
  const float* b1 = (const float*)d_in[3];   // [64,256]
  float* out = (float*)d_out;                // [4096,256] fp32

  // ws: Wt 514 chunks x 16 KB = 8.22 MB | Xt 2 MB | Qt 0.5 MB  (~10.8 MB total)
  f16* Wt = (f16*)d_ws;
  f16* Xt = (f16*)((char*)d_ws + (size_t)514 * 16384);
  f16* Qt = (f16*)((char*)d_ws + (size_t)514 * 16384 + (size_t)64 * 32768);

  hipMemsetAsync(out, 0, (size_t)NROWS * 256 * sizeof(float), stream);
  prep<<<658, 256, 0, stream>>>(W1, x, q, b1, Wt, Xt, Qt);
  mlp_main<<<(NROWS / MBLK) * SPLIT, 256, 0, stream>>>(q, Wt, Xt, Qt, out);
}

// Round 2
// 136.217 us; speedup vs baseline: 1.0806x; 1.0806x over previous
//
#include <hip/hip_runtime.h>
#include <stdint.h>

// out[n,o] = sum_{d,i} q[n,d] x[n,i] W1[d,i,o] + (q @ b1)[n,o]
// GEMM M=4096 N=256 K=16384 (k=d*256+i), fp16 MFMA 32x32x16, fp32 accum.
// A-frag = x-frag * q[row,d] per-lane scalar. Bias folded into sg0 as 2 extra
// K-chunks with A-frag = q-frag.
//
// ROUND 2: (a) atomic split-K epilogue -> fp32 partials (8 stripes in ws) +
// reduce kernel (atomics were memory-side serialized: WRITE_SIZE 35 MB = 1
// HBM-level RMW per atomicAdd); (b) depth-3 register prefetch of W chunks
// (4 static buffers, 16-step unrolled body); (c) per-block chunk-walk stagger
// (ic0 = (mb&3)*2) so ~16 not 64 blocks/XCD hammer the same L2 lines;
// (d) x and q read directly from fp32 (Xt/Qt prep removed; prep = W+bias only).

typedef _Float16 f16;
typedef f16 f16x8 __attribute__((ext_vector_type(8)));
typedef float f32x16 __attribute__((ext_vector_type(16)));

#define NROWS 4096
#define QDIM 64

// Wt chunk map: sg0 -> chunks 0..63, bias(b1) -> 64,65, sg>=1 -> 66+(sg-1)*64 ...
// chunk layout (16 KB): element ((s*2+h)*256+n)*8+j  <-  B[k = s*16+h*8+j][n]
__global__ __launch_bounds__(256) void prep(const float* __restrict__ W,
                                            const float* __restrict__ B1,
                                            f16* __restrict__ Wt) {
  const int b = blockIdx.x, t = threadIdx.x;
  if (b < 512) {
    const int sg = b >> 6, ic = (b >> 3) & 7, dd = b & 7;
    const int g = b + (sg ? 2 : 0);  // skip the 2 bias chunks
    const int k0 = ((sg << 3) + dd) * 256 + (ic << 5);
#pragma unroll
    for (int r = 0; r < 4; ++r) {
      const int gidx = (r << 8) + t;  // (s*2+h)*256 + n
      const int n = gidx & 255, sh = gidx >> 8;
      f16x8 h;
#pragma unroll
      for (int j = 0; j < 8; ++j)
        h[j] = (f16)W[(size_t)(k0 + (sh << 3) + j) * 256 + n];  // coalesced over n
      *(f16x8*)(Wt + (size_t)g * 8192 + (size_t)gidx * 8) = h;
    }
  } else {
    // b1 -> Wt chunks 64,65: B[k=cc*32+sh*8+j][n] = b1[k][n]
    const int cc = b - 512;
#pragma unroll
    for (int r = 0; r < 4; ++r) {
      const int gidx = (r << 8) + t;
      const int n = gidx & 255, sh = gidx >> 8;
      f16x8 h;
#pragma unroll
      for (int j = 0; j < 8; ++j)
        h[j] = (f16)B1[(size_t)((cc << 5) + (sh << 3) + j) * 256 + n];
      *(f16x8*)(Wt + (size_t)(64 + cc) * 8192 + (size_t)gidx * 8) = h;
    }
  }
}

// W frags of one chunk -> 4 f16x8 regs. P includes per-lane base
// wl = hf*4096 + w*1024 + l31*16. Index [s*2+nt]: nt:+512, s:+8192.
#define LOADW(D, P)                          \
  do {                                       \
    D[0] = *(const f16x8*)(P);               \
    D[1] = *(const f16x8*)((P) + 512);       \
    D[2] = *(const f16x8*)((P) + 8192);      \
    D[3] = *(const f16x8*)((P) + 8704);      \
  } while (0)

// one x fragment: 8 consecutive fp32 -> f16x8 (2 x float4 + cvt)
#define XFRAG(DST, PTR)                                                \
  do {                                                                 \
    float4 a_ = *(const float4*)(PTR);                                 \
    float4 b_ = *(const float4*)((PTR) + 4);                           \
    f16x8 h_;                                                          \
    h_[0] = (f16)a_.x; h_[1] = (f16)a_.y; h_[2] = (f16)a_.z;           \
    h_[3] = (f16)a_.w; h_[4] = (f16)b_.x; h_[5] = (f16)b_.y;           \
    h_[6] = (f16)b_.z; h_[7] = (f16)b_.w;                              \
    DST = h_;                                                          \
  } while (0)

// x frags for one ic, direct from fp32 X. Index [s*2+mt].
// element = x[mb*64 + mt*32 + l31][ic*32 + s*16 + hf*8 + j]
// xr0 = X + (mb*64 + l31)*256 + hf*8 ; mt:+8192 floats ; s:+16 floats.
#define LOADX_F(D, IC)                                  \
  do {                                                  \
    const float* xb_ = xr0 + ((IC) << 5);               \
    XFRAG(D[0], xb_);                                   \
    XFRAG(D[1], xb_ + 8192);                            \
    XFRAG(D[2], xb_ + 16);                              \
    XFRAG(D[3], xb_ + 8208);                            \
  } while (0)

// 8 MFMAs for one chunk: A = x-frag * q scalar. XF[s*2+mt], WW[s*2+nt].
#define MFMA8(XF, DD, WW)                                                        \
  do {                                                                           \
    const f16 q0_ = qr[0][DD], q1_ = qr[1][DD];                                  \
    f16x8 a00_ = XF[0] * q0_, a10_ = XF[1] * q1_;                                \
    f16x8 a01_ = XF[2] * q0_, a11_ = XF[3] * q1_;                                \
    acc[0][0] = __builtin_amdgcn_mfma_f32_32x32x16_f16(a00_, WW[0], acc[0][0], 0, 0, 0); \
    acc[1][0] = __builtin_amdgcn_mfma_f32_32x32x16_f16(a10_, WW[0], acc[1][0], 0, 0, 0); \
    acc[0][1] = __builtin_amdgcn_mfma_f32_32x32x16_f16(a00_, WW[1], acc[0][1], 0, 0, 0); \
    acc[1][1] = __builtin_amdgcn_mfma_f32_32x32x16_f16(a10_, WW[1], acc[1][1], 0, 0, 0); \
    acc[0][0] = __builtin_amdgcn_mfma_f32_32x32x16_f16(a01_, WW[2], acc[0][0], 0, 0, 0); \
    acc[1][0] = __builtin_amdgcn_mfma_f32_32x32x16_f16(a11_, WW[2], acc[1][0], 0, 0, 0); \
    acc[0][1] = __builtin_amdgcn_mfma_f32_32x32x16_f16(a01_, WW[3], acc[0][1], 0, 0, 0); \
    acc[1][1] = __builtin_amdgcn_mfma_f32_32x32x16_f16(a11_, WW[3], acc[1][1], 0, 0, 0); \
  } while (0)

// Bias variant: A = q fragment directly. QF[s*2+mt].
#define MFMA8Q(QF, WW)                                                           \
  do {                                                                           \
    acc[0][0] = __builtin_amdgcn_mfma_f32_32x32x16_f16(QF[0], WW[0], acc[0][0], 0, 0, 0); \
    acc[1][0] = __builtin_amdgcn_mfma_f32_32x32x16_f16(QF[1], WW[0], acc[1][0], 0, 0, 0); \
    acc[0][1] = __builtin_amdgcn_mfma_f32_32x32x16_f16(QF[0], WW[1], acc[0][1], 0, 0, 0); \
    acc[1][1] = __builtin_amdgcn_mfma_f32_32x32x16_f16(QF[1], WW[1], acc[1][1], 0, 0, 0); \
    acc[0][0] = __builtin_amdgcn_mfma_f32_32x32x16_f16(QF[2], WW[2], acc[0][0], 0, 0, 0); \
    acc[1][0] = __builtin_amdgcn_mfma_f32_32x32x16_f16(QF[3], WW[2], acc[1][0], 0, 0, 0); \
    acc[0][1] = __builtin_amdgcn_mfma_f32_32x32x16_f16(QF[2], WW[3], acc[0][1], 0, 0, 0); \
    acc[1][1] = __builtin_amdgcn_mfma_f32_32x32x16_f16(QF[3], WW[3], acc[1][1], 0, 0, 0); \
  } while (0)

// one pipeline step: load chunk seq(K+3) into LB, MFMA chunk seq(K) from UB
#define STEP(LB, ADDR, XF, DD, UB)   \
  do {                               \
    LOADW(LB, (ADDR));               \
    MFMA8(XF, DD, UB);               \
  } while (0)

// ---- main GEMM: 512 blocks = 8 split groups (XCD-affine %8) x 64 row-blocks ----
__global__ __launch_bounds__(256, 2) void mlp_main(const float* __restrict__ Q,
                                                   const float* __restrict__ X,
                                                   const f16* __restrict__ Wt,
                                                   float* __restrict__ Pp,
                                                   float* __restrict__ out,
                                                   int useP) {
  const int bid = blockIdx.x;
  const int sg = bid & 7;
  const int mb = bid >> 3;
  const int t = threadIdx.x;
  const int w = t >> 6;
  const int l = t & 63;
  const int l31 = l & 31;
  const int hf = l >> 5;

  // W slice base for this sg (+2 skips the bias chunks for sg>=1)
  const char* wg = (const char*)(Wt + (size_t)((sg << 6) + (sg ? 2 : 0)) * 8192);
  const int wl = (hf << 12) + (w << 10) + (l31 << 4);
  const char* wgl = wg + wl;

  // per-lane x base (direct fp32)
  const float* xr0 = X + (size_t)((mb << 6) + l31) * 256 + (hf << 3);

  // per-lane q scalars: q[mb*64 + mt*32 + l31][sg*8 + dd]
  f16 qr[2][8];
#pragma unroll
  for (int mt = 0; mt < 2; ++mt) {
    const float* qp = Q + (size_t)((mb << 6) + (mt << 5) + l31) * QDIM + (sg << 3);
#pragma unroll
    for (int dd = 0; dd < 8; ++dd) qr[mt][dd] = (f16)qp[dd];
  }

  f32x16 acc[2][2];
#pragma unroll
  for (int a = 0; a < 2; ++a)
#pragma unroll
    for (int bq = 0; bq < 2; ++bq)
#pragma unroll
      for (int r = 0; r < 16; ++r) acc[a][bq][r] = 0.f;

  f16x8 Wb0[4], Wb1[4], Wb2[4], Wb3[4], xfA[4], xfB[4];

  // staggered start: 4 groups of blocks begin at different ic positions
  const int ic0 = (mb & 3) << 1;

  // prologue: chunks seq0..2 (chunk = icP*8+dd; seq order is ic-rotated)
  LOADW(Wb0, wgl + ((size_t)ic0 << 17));
  LOADW(Wb1, wgl + ((size_t)ic0 << 17) + 16384);
  LOADW(Wb2, wgl + ((size_t)ic0 << 17) + 32768);
  LOADX_F(xfA, ic0);

  for (int so = 0; so < 4; ++so) {
    const int icP = (ic0 + (so << 1)) & 7;  // even; pair = (icP, icP+1)
    const char* cpb = wgl + ((size_t)icP << 17);
    // next pair's base; after the last pair -> bias region (chunks 64,65)
    const char* cpn = (so == 3) ? wgl + ((size_t)64 << 14)
                                : wgl + ((size_t)((icP + 2) & 7) << 17);
    LOADX_F(xfB, icP + 1);  // used at steps 8..15
    STEP(Wb3, cpb + (3 << 14),  xfA, 0, Wb0);
    STEP(Wb0, cpb + (4 << 14),  xfA, 1, Wb1);
    STEP(Wb1, cpb + (5 << 14),  xfA, 2, Wb2);
    STEP(Wb2, cpb + (6 << 14),  xfA, 3, Wb3);
    STEP(Wb3, cpb + (7 << 14),  xfA, 4, Wb0);
    STEP(Wb0, cpb + (8 << 14),  xfA, 5, Wb1);
    STEP(Wb1, cpb + (9 << 14),  xfA, 6, Wb2);
    STEP(Wb2, cpb + (10 << 14), xfA, 7, Wb3);
    LOADX_F(xfA, (icP + 2) & 7);  // next even ic (so==3: dummy, unused)
    STEP(Wb3, cpb + (11 << 14), xfB, 0, Wb0);
    STEP(Wb0, cpb + (12 << 14), xfB, 1, Wb1);
    STEP(Wb1, cpb + (13 << 14), xfB, 2, Wb2);
    STEP(Wb2, cpb + (14 << 14), xfB, 3, Wb3);
    STEP(Wb3, cpb + (15 << 14), xfB, 4, Wb0);
    STEP(Wb0, cpn,              xfB, 5, Wb1);
    STEP(Wb1, cpn + (1 << 14),  xfB, 6, Wb2);
    STEP(Wb2, cpn + (2 << 14),  xfB, 7, Wb3);
  }
  // exit invariant: Wb0 = bias chunk 64, Wb1 = bias chunk 65 (sg0's wg)

  // bias tail (sg0 only): A = q-frags straight from fp32 Q
  if (sg == 0) {
    f16x8 QF0[4], QF1[4];
    const float* qb = Q + (size_t)((mb << 6) + l31) * QDIM + (hf << 3);
    XFRAG(QF0[0], qb);            // s=0,mt=0 : k=0..31 chunk
    XFRAG(QF0[1], qb + 32 * QDIM);
    XFRAG(QF0[2], qb + 16);
    XFRAG(QF0[3], qb + 16 + 32 * QDIM);
    XFRAG(QF1[0], qb + 32);       // k=32..63 chunk
    XFRAG(QF1[1], qb + 32 + 32 * QDIM);
    XFRAG(QF1[2], qb + 48);
    XFRAG(QF1[3], qb + 48 + 32 * QDIM);
    MFMA8Q(QF0, Wb0);
    MFMA8Q(QF1, Wb1);
  }

  // epilogue: partial stripe (plain stores) or atomic fallback.
  // C/D (32x32): col = lane&31, row = (reg&3) + 8*(reg>>2) + 4*(lane>>5)
  if (useP) {
    float* const ob = Pp + ((size_t)sg << 20);
#pragma unroll
    for (int mt = 0; mt < 2; ++mt)
#pragma unroll
      for (int nt = 0; nt < 2; ++nt)
#pragma unroll
        for (int r = 0; r < 16; ++r) {
          const int row = (mb << 6) + (mt << 5) + (r & 3) + ((r >> 2) << 3) + (hf << 2);
          const int col = (w << 6) + (nt << 5) + l31;
          ob[(size_t)row * 256 + col] = acc[mt][nt][r];
        }
  } else {
#pragma unroll
    for (int mt = 0; mt < 2; ++mt)
#pragma unroll
      for (int nt = 0; nt < 2; ++nt)
#pragma unroll
        for (int r = 0; r < 16; ++r) {
          const int row = (mb << 6) + (mt << 5) + (r & 3) + ((r >> 2) << 3) + (hf << 2);
          const int col = (w << 6) + (nt << 5) + l31;
          atomicAdd(out + (size_t)row * 256 + col, acc[mt][nt][r]);
        }
  }
}

// sum the 8 split-K stripes -> out. 1024 blocks x 256 threads x float4.
__global__ __launch_bounds__(256) void reduce_k(const float* __restrict__ P,
                                                float* __restrict__ out) {
  const size_t i = (((size_t)blockIdx.x << 8) + threadIdx.x) << 2;
  float4 s = *(const float4*)(P + i);
#pragma unroll
  for (int g = 1; g < 8; ++g) {
    float4 v = *(const float4*)(P + ((size_t)g << 20) + i);
    s.x += v.x; s.y += v.y; s.z += v.z; s.w += v.w;
  }
  *(float4*)(out + i) = s;
}

extern "C" void kernel_launch(void* const* d_in, const int* in_sizes, int n_in,
                              void* d_out, int out_size, void* d_ws, size_t ws_size,
                              hipStream_t stream) {
  (void)in_sizes; (void)n_in; (void)out_size;
  const float* x  = (const float*)d_in[0];   // [4096,256]
  const float* q  = (const float*)d_in[1];   // [4096,64]
  const float* W1 = (const float*)d_in[2];   // [64,256,256]
  const float* b1 = (const float*)d_in[3];   // [64,256]
  float* out = (float*)d_out;                // [4096,256] fp32

  // ws: Wt 514 chunks x 16 KB = 8.42 MB | partials 8 x 4 MB = 33.55 MB
  const size_t WT_BYTES = (size_t)514 * 16384;
  const size_t NEED = WT_BYTES + ((size_t)8 << 22);
  const int useP = (ws_size >= NEED) ? 1 : 0;
  f16* Wt = (f16*)d_ws;
  float* Pp = (float*)((char*)d_ws + WT_BYTES);

  if (!useP)
    hipMemsetAsync(out, 0, (size_t)NROWS * 256 * sizeof(float), stream);
  prep<<<514, 256, 0, stream>>>(W1, b1, Wt);
  mlp_main<<<512, 256, 0, stream>>>(q, x, Wt, Pp, out, useP);
  if (useP) reduce_k<<<1024, 256, 0, stream>>>(Pp, out);
}

// Round 3
// 129.089 us; speedup vs baseline: 1.1402x; 1.0552x over previous
//
#include <hip/hip_runtime.h>
#include <stdint.h>

// out[n,o] = sum_{d,i} q[n,d] x[n,i] W1[d,i,o] + (q @ b1)[n,o]
// GEMM M=4096 N=256 K=16384 (k=d*256+i), fp16 MFMA 32x32x16, fp32 accum.
// A-frag = x-frag * q[row,d] per-lane scalar. Bias folded into sg 0 as 2 extra
// K-chunks with A-frag = q-frag.
//
// ROUND 3: W traffic halved via MBLK=128 (W bytes = (M/MBLK) * 8.4 MB,
// independent of SPLIT). SPLIT=16 keeps grid at 512 (2 blocks/CU, 2
// waves/SIMD). Compute floor: 2 waves x 512 MFMA x 32cy = 13.7 us/SIMD.
// x is pre-converted to f16 (Xt) to halve the x stream; per-CU L1 demand
// drops from ~64+ B/cy (ceiling) to ~48 B/cy. Partials: 16 fp32 stripes
// (runtime fallback: f16 stripes, then atomics, by ws_size).

typedef _Float16 f16;
typedef f16 f16x8 __attribute__((ext_vector_type(8)));
typedef float f32x16 __attribute__((ext_vector_type(16)));

#define NROWS 4096
#define QDIM 64
#define MBLK 128
#define SPLIT 16

// ---------------- prep ----------------
// Wt chunk map (unchanged): chunks (sg8*64 + ic*8 + dd8) + (sg8?2:0); bias k=0..63
// of b1 at chunks 64,65. Chunk layout (16 KB): elem ((s*2+h)*256+n)*8+j <-
// B[k=s*16+h*8+j][n].
// Xt layout: elem mb*32768 + (((ic*2+s)*2+h)*128 + row)*8 + j
//          <- x[mb*128+row][ic*32+s*16+h*8+j]   (note k = ish*8+j, ish=(ic*2+s)*2+h)
// grid 642: [0,512) W | [512,514) b1 | [514,642) Xt
__global__ __launch_bounds__(256) void prep(const float* __restrict__ W,
                                            const float* __restrict__ B1,
                                            const float* __restrict__ X,
                                            f16* __restrict__ Wt,
                                            f16* __restrict__ Xt) {
  const int b = blockIdx.x, t = threadIdx.x;
  if (b < 512) {
    const int sg = b >> 6, ic = (b >> 3) & 7, dd = b & 7;
    const int g = b + (sg ? 2 : 0);
    const int k0 = ((sg << 3) + dd) * 256 + (ic << 5);
#pragma unroll
    for (int r = 0; r < 4; ++r) {
      const int gidx = (r << 8) + t;  // (s*2+h)*256 + n
      const int n = gidx & 255, sh = gidx >> 8;
      f16x8 h;
#pragma unroll
      for (int j = 0; j < 8; ++j)
        h[j] = (f16)W[(size_t)(k0 + (sh << 3) + j) * 256 + n];  // coalesced over n
      *(f16x8*)(Wt + (size_t)g * 8192 + (size_t)gidx * 8) = h;
    }
  } else if (b < 514) {
    const int cc = b - 512;
#pragma unroll
    for (int r = 0; r < 4; ++r) {
      const int gidx = (r << 8) + t;
      const int n = gidx & 255, sh = gidx >> 8;
      f16x8 h;
#pragma unroll
      for (int j = 0; j < 8; ++j)
        h[j] = (f16)B1[(size_t)((cc << 5) + (sh << 3) + j) * 256 + n];
      *(f16x8*)(Wt + (size_t)(64 + cc) * 8192 + (size_t)gidx * 8) = h;
    }
  } else {
    // Xt: 128 blocks, 4 per mb-tile (32 tiles of 128 rows x 256 k)
    const int idx = b - 514;
    const int mb = idx >> 2, qtr = idx & 3;
#pragma unroll
    for (int r = 0; r < 4; ++r) {
      const int u = (qtr << 10) + (r << 8) + t;  // 0..4095 per tile
      const int row = u & 127, ish = u >> 7;     // k = ish*8 + j
      const float* src = X + (size_t)((mb << 7) + row) * 256 + (ish << 3);
      float4 a = *(const float4*)src;
      float4 c = *(const float4*)(src + 4);
      f16x8 h;
      h[0] = (f16)a.x; h[1] = (f16)a.y; h[2] = (f16)a.z; h[3] = (f16)a.w;
      h[4] = (f16)c.x; h[5] = (f16)c.y; h[6] = (f16)c.z; h[7] = (f16)c.w;
      *(f16x8*)(Xt + (size_t)mb * 32768 + (size_t)u * 8) = h;
    }
  }
}

// W frags of one chunk -> 4 regs, index [s*2+nt]. P includes lane base
// wl = hf*4096 + w*1024 + l31*16. nt:+512, s:+8192.
#define LOADW(D, P)                          \
  do {                                       \
    D[0] = *(const f16x8*)(P);               \
    D[1] = *(const f16x8*)((P) + 512);       \
    D[2] = *(const f16x8*)((P) + 8192);      \
    D[3] = *(const f16x8*)((P) + 8704);      \
  } while (0)

// x frags for one ic from f16 Xt, index [s*4+mt].
// xg includes mb*65536 + hf*2048 + l31*16 (bytes). ic:+8192, s:+4096, mt:+512.
#define LOADX(D, IC)                                         \
  do {                                                       \
    const char* xb_ = xg + ((IC) << 13);                     \
    _Pragma("unroll")                                        \
    for (int s_ = 0; s_ < 2; ++s_)                           \
      _Pragma("unroll")                                      \
      for (int mt_ = 0; mt_ < 4; ++mt_)                      \
        D[s_ * 4 + mt_] =                                    \
            *(const f16x8*)(xb_ + (s_ << 12) + (mt_ << 9));  \
  } while (0)

// one fp32-float8 -> f16x8
#define XFRAG(DST, PTR)                                      \
  do {                                                       \
    float4 a_ = *(const float4*)(PTR);                       \
    float4 b_ = *(const float4*)((PTR) + 4);                 \
    f16x8 h_;                                                \
    h_[0] = (f16)a_.x; h_[1] = (f16)a_.y; h_[2] = (f16)a_.z; \
    h_[3] = (f16)a_.w; h_[4] = (f16)b_.x; h_[5] = (f16)b_.y; \
    h_[6] = (f16)b_.z; h_[7] = (f16)b_.w;                    \
    DST = h_;                                                \
  } while (0)

// 16 MFMAs for one chunk: A = x-frag * q scalar. XF[s*4+mt], WW[s*2+nt].
#define MFMA16(XF, DD, WW)                                                      \
  do {                                                                          \
    _Pragma("unroll")                                                           \
    for (int s_ = 0; s_ < 2; ++s_) {                                            \
      _Pragma("unroll")                                                         \
      for (int mt_ = 0; mt_ < 4; ++mt_) {                                       \
        f16x8 a_ = XF[s_ * 4 + mt_] * qr[mt_][DD];                              \
        acc[mt_][0] = __builtin_amdgcn_mfma_f32_32x32x16_f16(                   \
            a_, WW[s_ * 2 + 0], acc[mt_][0], 0, 0, 0);                          \
        acc[mt_][1] = __builtin_amdgcn_mfma_f32_32x32x16_f16(                   \
            a_, WW[s_ * 2 + 1], acc[mt_][1], 0, 0, 0);                          \
      }                                                                         \
    }                                                                           \
  } while (0)

// bias variant: A = q-frag directly
#define MFMA16Q(QF, WW)                                                         \
  do {                                                                          \
    _Pragma("unroll")                                                           \
    for (int s_ = 0; s_ < 2; ++s_) {                                            \
      _Pragma("unroll")                                                         \
      for (int mt_ = 0; mt_ < 4; ++mt_) {                                       \
        acc[mt_][0] = __builtin_amdgcn_mfma_f32_32x32x16_f16(                   \
            QF[s_ * 4 + mt_], WW[s_ * 2 + 0], acc[mt_][0], 0, 0, 0);            \
        acc[mt_][1] = __builtin_amdgcn_mfma_f32_32x32x16_f16(                   \
            QF[s_ * 4 + mt_], WW[s_ * 2 + 1], acc[mt_][1], 0, 0, 0);            \
      }                                                                         \
    }                                                                           \
  } while (0)

// ---- main GEMM: 512 blocks = 16 split groups (XCD-affine &7) x 32 row-blocks ----
// sg16 covers d in [sg16*4, sg16*4+4) -> K=1024 = 8 ic x 4 dd = 32 chunks.
__global__ __launch_bounds__(256, 2) void mlp_main(const float* __restrict__ Q,
                                                   const f16* __restrict__ Wt,
                                                   const f16* __restrict__ Xt,
                                                   void* __restrict__ Pp,
                                                   float* __restrict__ out,
                                                   int mode) {
  const int bid = blockIdx.x;
  const int sg16 = bid & 15;
  const int mb = bid >> 4;  // 0..31, 128-row tiles
  const int t = threadIdx.x;
  const int w = t >> 6;     // n-quarter (64 cols)
  const int l = t & 63;
  const int l31 = l & 31;
  const int hf = l >> 5;

  const int sg8 = sg16 >> 1;
  const int dd8b = (sg16 & 1) << 2;  // dd8 base (0 or 4)
  const int wl = (hf << 12) + (w << 10) + (l31 << 4);
  // chunk(ic,dd) = wrow + ic*131072 + dd*16384
  const char* wrow = (const char*)Wt +
      (((size_t)(sg8 * 64 + (sg8 ? 2 : 0) + dd8b)) << 14) + wl;

  const char* xg = (const char*)Xt + ((size_t)mb << 16) + (hf << 11) + (l31 << 4);

  // per-lane q scalars: q[mb*128 + mt*32 + l31][sg16*4 + dd], dd<4 (one float4)
  f16 qr[4][4];
#pragma unroll
  for (int mt = 0; mt < 4; ++mt) {
    float4 qv = *(const float4*)(Q + (size_t)((mb << 7) + (mt << 5) + l31) * QDIM +
                                 (sg16 << 2));
    qr[mt][0] = (f16)qv.x; qr[mt][1] = (f16)qv.y;
    qr[mt][2] = (f16)qv.z; qr[mt][3] = (f16)qv.w;
  }

  f32x16 acc[4][2];
#pragma unroll
  for (int a = 0; a < 4; ++a)
#pragma unroll
    for (int bq = 0; bq < 2; ++bq)
#pragma unroll
      for (int r = 0; r < 16; ++r) acc[a][bq][r] = 0.f;

  f16x8 WA[4], WB[4], xfA[8], xfB[8];

  // stagger: 4 ic phases across same-sg blocks (8 blocks/XCD per phase)
  const int ic0 = (mb & 3) << 1;  // even

  LOADW(WA, wrow + ((size_t)ic0 << 17));
  LOADX(xfA, ic0);

  for (int so = 0; so < 4; ++so) {
    const int icE = (ic0 + (so << 1)) & 7;  // even
    const int icO = icE + 1;                // <= 7
    const char* pe = wrow + ((size_t)icE << 17);
    const char* po = wrow + ((size_t)icO << 17);
    // last in-loop load: sg0 -> bias chunk 64; others -> harmless dummy
    const char* pn = (so == 3)
                         ? ((sg16 == 0) ? (const char*)Wt + ((size_t)64 << 14) + wl : pe)
                         : wrow + ((size_t)((icE + 2) & 7) << 17);
    LOADX(xfB, icO);
    LOADW(WB, pe + 16384);  MFMA16(xfA, 0, WA);
    LOADW(WA, pe + 32768);  MFMA16(xfA, 1, WB);
    LOADW(WB, pe + 49152);  MFMA16(xfA, 2, WA);
    LOADW(WA, po);          MFMA16(xfA, 3, WB);
    LOADX(xfA, (icE + 2) & 7);  // so==3: dummy reload (unused)
    LOADW(WB, po + 16384);  MFMA16(xfB, 0, WA);
    LOADW(WA, po + 32768);  MFMA16(xfB, 1, WB);
    LOADW(WB, po + 49152);  MFMA16(xfB, 2, WA);
    LOADW(WA, pn);          MFMA16(xfB, 3, WB);
  }
  // exit: for sg16==0, WA = bias chunk 64

  if (sg16 == 0) {
    const char* b65 = (const char*)Wt + ((size_t)65 << 14) + wl;
    LOADW(WB, b65);
    f16x8 QF[8];
    // chunk 64: k = 0*32 + s*16 + hf*8 + j of q
#pragma unroll
    for (int s = 0; s < 2; ++s)
#pragma unroll
      for (int mt = 0; mt < 4; ++mt)
        XFRAG(QF[s * 4 + mt],
              Q + (size_t)((mb << 7) + (mt << 5) + l31) * QDIM + (s << 4) + (hf << 3));
    MFMA16Q(QF, WA);
    // chunk 65: k = 32 + s*16 + hf*8 + j
#pragma unroll
    for (int s = 0; s < 2; ++s)
#pragma unroll
      for (int mt = 0; mt < 4; ++mt)
        XFRAG(QF[s * 4 + mt],
              Q + (size_t)((mb << 7) + (mt << 5) + l31) * QDIM + 32 + (s << 4) + (hf << 3));
    MFMA16Q(QF, WB);
  }

  // epilogue. C/D (32x32): col = lane&31, row = (reg&3) + 8*(reg>>2) + 4*(lane>>5)
  if (mode == 2) {
    float* P = (float*)Pp + ((size_t)sg16 << 20);  // fp32 stripe, 4 MB
#pragma unroll
    for (int mt = 0; mt < 4; ++mt)
#pragma unroll
      for (int nt = 0; nt < 2; ++nt)
#pragma unroll
        for (int r = 0; r < 16; ++r) {
          const int row = (mb << 7) + (mt << 5) + (r & 3) + ((r >> 2) << 3) + (hf << 2);
          const int col = (w << 6) + (nt << 5) + l31;
          P[(size_t)row * 256 + col] = acc[mt][nt][r];
        }
  } else if (mode == 1) {
    f16* P = (f16*)Pp + ((size_t)sg16 << 20);  // f16 stripe, 2 MB
#pragma unroll
    for (int mt = 0; mt < 4; ++mt)
#pragma unroll
      for (int nt = 0; nt < 2; ++nt)
#pragma unroll
        for (int r = 0; r < 16; ++r) {
          const int row = (mb << 7) + (mt << 5) + (r & 3) + ((r >> 2) << 3) + (hf << 2);
          const int col = (w << 6) + (nt << 5) + l31;
          P[(size_t)row * 256 + col] = (f16)acc[mt][nt][r];
        }
  } else {
#pragma unroll
    for (int mt = 0; mt < 4; ++mt)
#pragma unroll
      for (int nt = 0; nt < 2; ++nt)
#pragma unroll
        for (int r = 0; r < 16; ++r) {
          const int row = (mb << 7) + (mt << 5) + (r & 3) + ((r >> 2) << 3) + (hf << 2);
          const int col = (w << 6) + (nt << 5) + l31;
          atomicAdd(out + (size_t)row * 256 + col, acc[mt][nt][r]);
        }
  }
}

// sum 16 fp32 stripes -> out. 1024 blocks x 256 threads x float4.
__global__ __launch_bounds__(256) void reduce32(const float* __restrict__ P,
                                                float* __restrict__ out) {
  const size_t i = (((size_t)blockIdx.x << 8) + threadIdx.x) << 2;
  float4 s = *(const float4*)(P + i);
#pragma unroll
  for (int g = 1; g < 16; ++g) {
    float4 v = *(const float4*)(P + ((size_t)g << 20) + i);
    s.x += v.x; s.y += v.y; s.z += v.z; s.w += v.w;
  }
  *(float4*)(out + i) = s;
}

// sum 16 f16 stripes -> out. 512 blocks x 256 threads x f16x8.
__global__ __launch_bounds__(256) void reduce16(const f16* __restrict__ P,
                                                float* __restrict__ out) {
  const size_t i8 = ((size_t)blockIdx.x << 8) + threadIdx.x;
  float s[8];
#pragma unroll
  for (int j = 0; j < 8; ++j) s[j] = 0.f;
#pragma unroll
  for (int g = 0; g < 16; ++g) {
    f16x8 v = *(const f16x8*)(P + ((size_t)g << 20) + (i8 << 3));
#pragma unroll
    for (int j = 0; j < 8; ++j) s[j] += (float)v[j];
  }
  float4 o0 = {s[0], s[1], s[2], s[3]};
  float4 o1 = {s[4], s[5], s[6], s[7]};
  *(float4*)(out + (i8 << 3)) = o0;
  *(float4*)(out + (i8 << 3) + 4) = o1;
}

extern "C" void kernel_launch(void* const* d_in, const int* in_sizes, int n_in,
                              void* d_out, int out_size, void* d_ws, size_t ws_size,
                              hipStream_t stream) {
  (void)in_sizes; (void)n_in; (void)out_size;
  const float* x  = (const float*)d_in[0];   // [4096,256]
  const float* q  = (const float*)d_in[1];   // [4096,64]
  const float* W1 = (const float*)d_in[2];   // [64,256,256]
  const float* b1 = (const float*)d_in[3];   // [64,256]
  float* out = (float*)d_out;                // [4096,256] fp32

  const size_t WT_BYTES = (size_t)514 * 16384;        // 8.42 MB
  const size_t XT_BYTES = (size_t)2 * 1024 * 1024;    // 2 MB
  const size_t P32_BYTES = (size_t)16 << 22;          // 64 MB
  const size_t P16_BYTES = (size_t)16 << 21;          // 32 MB

  f16* Wt = (f16*)d_ws;
  f16* Xt = (f16*)((char*)d_ws + WT_BYTES);
  void* Pp = (void*)((char*)d_ws + WT_BYTES + XT_BYTES);

  int mode;
  if (ws_size >= WT_BYTES + XT_BYTES + P32_BYTES) mode = 2;
  else if (ws_size >= WT_BYTES + XT_BYTES + P16_BYTES) mode = 1;
  else mode = 0;

  if (mode == 0)
    hipMemsetAsync(out, 0, (size_t)NROWS * 256 * sizeof(float), stream);
  prep<<<642, 256, 0, stream>>>(W1, b1, x, Wt, Xt);
  mlp_main<<<512, 256, 0, stream>>>(q, Wt, Xt, Pp, out, mode);
  if (mode == 2)      reduce32<<<1024, 256, 0, stream>>>((const float*)Pp, out);
  else if (mode == 1) reduce16<<<512, 256, 0, stream>>>((const f16*)Pp, out);
}

// Round 5
// 120.583 us; speedup vs baseline: 1.2207x; 1.0705x over previous
//
#include <hip/hip_runtime.h>
#include <stdint.h>

// out[n,o] = sum_{d,i} q[n,d] x[n,i] W1[d,i,o] + (q @ b1)[n,o]
// GEMM M=4096 N=256 K=16384 (k = d*256 + i), fp16 MFMA 32x32x16, fp32 accum.
//
// ROUND 5 = ROUND 4 + workspace-overlap fix. Bt is 32 KB (8 nc x 4 kc x 1 KB),
// round 4 reserved only 16 KB -> Bt overlapped Xt's first 16 KB (mb 0 x-frags
// raced with b1 staging; absmax 42). Xt now starts at +32 KB.
//
// Structure: full-K blocks. Tile = 64 rows x 32 cols, grid 512 = 64 mb x 8 nc
// (nc = bid&7 -> XCD-affine 1 MB W column slice, L2-resident per XCD).
// The 4 waves split K (d-ranges of 16); partials combined via one LDS
// reduction + direct fp32 stores: NO split-K stripes, NO reduce kernel, NO
// memset -> 2 dispatches total.
// Per chunk (16 k's): 1 B-frag load (dwordx4) + 2 MFMA. Depth-16 register
// ring on W (1024 cy latency coverage vs round-3's 516 at depth-1). ic-stagger
// (mb&7)*2 de-synchronizes same-nc blocks walking the same L2 lines.
// Bias q@b1 added by wave 0 only, as 4 extra MFMA chunks (A = q-frag).

typedef _Float16 f16;
typedef f16 f16x8 __attribute__((ext_vector_type(8)));
typedef float f32x16 __attribute__((ext_vector_type(16)));

#define QDIM 64

// one fp32-float8 -> f16x8
#define XFRAG(DST, PTR)                                      \
  do {                                                       \
    float4 a_ = *(const float4*)(PTR);                       \
    float4 b_ = *(const float4*)((PTR) + 4);                 \
    f16x8 h_;                                                \
    h_[0] = (f16)a_.x; h_[1] = (f16)a_.y; h_[2] = (f16)a_.z; \
    h_[3] = (f16)a_.w; h_[4] = (f16)b_.x; h_[5] = (f16)b_.y; \
    h_[6] = (f16)b_.z; h_[7] = (f16)b_.w;                    \
    DST = h_;                                                \
  } while (0)

// ---------------- prep ----------------
// Wt layout (8 MB):  byte = ((nc*64 + d)*16 + ic)*1024 + hf*512 + c*16 + j*2
//   <- W1[d][ic*16 + hf*8 + j][nc*32 + c]      (B-frag lane-linear, 1KB chunks)
// Xt layout (2 MB):  byte = ((mb*16 + ic)*2 + hf)*1024 + row*16 + j*2
//   <- x[mb*64 + row][ic*16 + hf*8 + j]        (A-frag lane-linear)
// Bt layout (32 KB): byte = ((nc*4 + kc)*2 + hf)*512 + c*16 + j*2
//   <- b1[kc*16 + hf*8 + j][nc*32 + c]
// grid 577: [0,512) W | [512,576) Xt | 576 Bt
__global__ __launch_bounds__(256) void prep(const float* __restrict__ W,
                                            const float* __restrict__ B1,
                                            const float* __restrict__ X,
                                            f16* __restrict__ Wt,
                                            f16* __restrict__ Xt,
                                            f16* __restrict__ Bt) {
  const int b = blockIdx.x, t = threadIdx.x;
  if (b < 512) {
    const int d = b >> 3, grp = b & 7;
#pragma unroll
    for (int r = 0; r < 4; ++r) {
      const int ib = (grp << 2) + r;  // i = ib*8 + j
      const float* src = W + ((size_t)d * 256 + ((size_t)ib << 3)) * 256 + t;
      f16x8 h;
#pragma unroll
      for (int j = 0; j < 8; ++j) h[j] = (f16)src[(size_t)j << 8];  // coalesced over t
      const int nc = t >> 5, c = t & 31, ic = ib >> 1, hb = ib & 1;
      *(f16x8*)((char*)Wt + ((((size_t)nc * 64 + d) * 16 + ic) << 10) +
                (hb << 9) + (c << 4)) = h;
    }
  } else if (b < 576) {
    const int mb = b - 512;
#pragma unroll
    for (int rep = 0; rep < 8; ++rep) {
      const int u = (rep << 8) + t;        // 0..2047
      const int row = u & 63, ish = u >> 6;  // ish 0..31, i = ish*8 + j
      const float* src = X + ((size_t)((mb << 6) + row)) * 256 + (ish << 3);
      f16x8 h;
      XFRAG(h, src);
      *(f16x8*)((char*)Xt + ((((size_t)mb * 16 + (ish >> 1)) * 2 + (ish & 1)) << 10) +
                (row << 4)) = h;  // writes coalesced (row-contiguous)
    }
  } else {
#pragma unroll
    for (int kb = 0; kb < 8; ++kb) {  // k = kb*8 + j
      const float* src = B1 + ((size_t)kb << 3) * 256 + t;
      f16x8 h;
#pragma unroll
      for (int j = 0; j < 8; ++j) h[j] = (f16)src[(size_t)j << 8];
      *(f16x8*)((char*)Bt + (((size_t)(t >> 5) * 4 + (kb >> 1)) << 10) +
                ((kb & 1) << 9) + ((t & 31) << 4)) = h;
    }
  }
}

// load x frags (mt=0,1) for actual ic
#define LOADX(D, IC)                                             \
  do {                                                           \
    D[0] = *(const f16x8*)(xb + ((size_t)(IC) << 11));           \
    D[1] = *(const f16x8*)(xb + ((size_t)(IC) << 11) + 512);     \
  } while (0)

// consume all 16 chunks of the ring (current ic), prefetch chunks of ICN.
// acc split even/odd dd -> dep distance 4 MFMAs.
#define FULL16(XF, ICN)                                                          \
  do {                                                                          \
    _Pragma("unroll")                                                           \
    for (int dq = 0; dq < 16; ++dq) {                                           \
      f16x8 wfr = Wr[dq];                                                       \
      Wr[dq] = *(const f16x8*)(wl + (((size_t)dq * 16 + (ICN)) << 10));         \
      f16x8 a0 = XF[0] * qr0[dq];                                               \
      acc0[dq & 1] = __builtin_amdgcn_mfma_f32_32x32x16_f16(                    \
          a0, wfr, acc0[dq & 1], 0, 0, 0);                                      \
      f16x8 a1 = XF[1] * qr1[dq];                                               \
      acc1[dq & 1] = __builtin_amdgcn_mfma_f32_32x32x16_f16(                    \
          a1, wfr, acc1[dq & 1], 0, 0, 0);                                      \
    }                                                                           \
  } while (0)

// ---- main: 512 blocks = 64 mb-tiles (64 rows) x 8 col-tiles (32 cols) ----
__global__ __launch_bounds__(256, 2) void mlp_main(const float* __restrict__ Q,
                                                   const f16* __restrict__ Wt,
                                                   const f16* __restrict__ Xt,
                                                   const f16* __restrict__ Bt,
                                                   float* __restrict__ out) {
  __shared__ __align__(16) float red[4][64][36];  // padded: conflict-light reduce

  const int bid = blockIdx.x;
  const int nc = bid & 7;   // XCD-affine column tile
  const int mb = bid >> 3;  // 64-row tile
  const int t = threadIdx.x;
  const int w = t >> 6;     // wave owns d-range [w*16, w*16+16)
  const int l = t & 63;
  const int l31 = l & 31;
  const int hf = l >> 5;

  // per-lane W base: chunk (dd, ic) at + (dd*16 + ic)*1024
  const char* wl = (const char*)Wt + (((size_t)(nc * 64 + (w << 4))) << 14) +
                   (hf << 9) + (l31 << 4);
  // per-lane x base: frag (mt, ic) at + ic*2048 + mt*512
  const char* xb = (const char*)Xt + ((size_t)mb << 15) + (hf << 10) + (l31 << 4);

  // q scalars for this wave's 16 d's, rows mt*32 + l31
  f16 qr0[16], qr1[16];
  {
    const float* qp0 = Q + ((size_t)((mb << 6) + l31)) * QDIM + (w << 4);
    const float* qp1 = qp0 + (size_t)32 * QDIM;
#pragma unroll
    for (int g = 0; g < 4; ++g) {
      float4 v0 = *(const float4*)(qp0 + (g << 2));
      float4 v1 = *(const float4*)(qp1 + (g << 2));
      qr0[g * 4 + 0] = (f16)v0.x; qr0[g * 4 + 1] = (f16)v0.y;
      qr0[g * 4 + 2] = (f16)v0.z; qr0[g * 4 + 3] = (f16)v0.w;
      qr1[g * 4 + 0] = (f16)v1.x; qr1[g * 4 + 1] = (f16)v1.y;
      qr1[g * 4 + 2] = (f16)v1.z; qr1[g * 4 + 3] = (f16)v1.w;
    }
  }

  f32x16 acc0[2], acc1[2];
#pragma unroll
  for (int p = 0; p < 2; ++p)
#pragma unroll
    for (int r = 0; r < 16; ++r) { acc0[p][r] = 0.f; acc1[p][r] = 0.f; }

  f16x8 Wr[16], xfA[2], xfB[2];

  // ic-stagger: same-nc blocks start at 8 different positions
  const int icoff = (mb & 7) << 1;

  LOADX(xfA, icoff);
#pragma unroll
  for (int dq = 0; dq < 16; ++dq)
    Wr[dq] = *(const f16x8*)(wl + (((size_t)dq * 16 + icoff) << 10));

  for (int ic2 = 0; ic2 < 8; ++ic2) {
    const int o  = ((ic2 << 1) + 1 + icoff) & 15;  // actual odd ic
    const int n2 = ((ic2 << 1) + 2 + icoff) & 15;  // actual next even ic
    LOADX(xfB, o);
    FULL16(xfA, o);       // consume even ic, prefetch odd
    LOADX(xfA, n2);       // ic2==7: dummy reload (unused)
    FULL16(xfB, n2);      // consume odd, prefetch next even (ic2==7: dummy)
  }

  // merge even/odd accumulator chains
#pragma unroll
  for (int r = 0; r < 16; ++r) {
    acc0[0][r] += acc0[1][r];
    acc1[0][r] += acc1[1][r];
  }

  // bias (wave 0 only): 4 chunks over QDIM, A = q-frag, B = Bt
  if (w == 0) {
#pragma unroll
    for (int kc = 0; kc < 4; ++kc) {
      f16x8 bf = *(const f16x8*)((const char*)Bt +
          (((size_t)nc * 4 + kc) << 10) + (hf << 9) + (l31 << 4));
      f16x8 q0, q1;
      XFRAG(q0, Q + ((size_t)((mb << 6) + l31)) * QDIM + (kc << 4) + (hf << 3));
      XFRAG(q1, Q + ((size_t)((mb << 6) + 32 + l31)) * QDIM + (kc << 4) + (hf << 3));
      acc0[0] = __builtin_amdgcn_mfma_f32_32x32x16_f16(q0, bf, acc0[0], 0, 0, 0);
      acc1[0] = __builtin_amdgcn_mfma_f32_32x32x16_f16(q1, bf, acc1[0], 0, 0, 0);
    }
  }

  // cross-wave K-reduction in LDS.
  // C/D (32x32): col = lane&31, row = (reg&3) + 8*(reg>>2) + 4*(lane>>5)
#pragma unroll
  for (int r = 0; r < 16; ++r) {
    const int row0 = (r & 3) + ((r >> 2) << 3) + (hf << 2);
    red[w][row0][l31] = acc0[0][r];
    red[w][32 + row0][l31] = acc1[0][r];
  }
  __syncthreads();

  const int row = t >> 2;            // 0..63
  const int cq = (t & 3) << 3;       // 0,8,16,24
  float s[8];
#pragma unroll
  for (int j = 0; j < 8; ++j) s[j] = 0.f;
#pragma unroll
  for (int wq = 0; wq < 4; ++wq) {
    const float* rp = &red[wq][row][cq];
    float4 v0 = *(const float4*)rp;
    float4 v1 = *(const float4*)(rp + 4);
    s[0] += v0.x; s[1] += v0.y; s[2] += v0.z; s[3] += v0.w;
    s[4] += v1.x; s[5] += v1.y; s[6] += v1.z; s[7] += v1.w;
  }
  float4 o0 = {s[0], s[1], s[2], s[3]};
  float4 o1 = {s[4], s[5], s[6], s[7]};
  float* op = out + ((size_t)((mb << 6) + row)) * 256 + (nc << 5) + cq;
  *(float4*)op = o0;
  *(float4*)(op + 4) = o1;
}

extern "C" void kernel_launch(void* const* d_in, const int* in_sizes, int n_in,
                              void* d_out, int out_size, void* d_ws, size_t ws_size,
                              hipStream_t stream) {
  (void)in_sizes; (void)n_in; (void)out_size; (void)ws_size;
  const float* x  = (const float*)d_in[0];   // [4096,256]
  const float* q  = (const float*)d_in[1];   // [4096,64]
  const float* W1 = (const float*)d_in[2];   // [64,256,256]
  const float* b1 = (const float*)d_in[3];   // [64,256]
  float* out = (float*)d_out;                // [4096,256] fp32

  // ws: Wt 8 MB | Bt 32 KB | Xt 2 MB  (~10.03 MB)
  f16* Wt = (f16*)d_ws;
  f16* Bt = (f16*)((char*)d_ws + ((size_t)8 << 20));
  f16* Xt = (f16*)((char*)d_ws + ((size_t)8 << 20) + 32768);  // Bt is 32 KB!

  prep<<<577, 256, 0, stream>>>(W1, b1, x, Wt, Xt, Bt);
  mlp_main<<<512, 256, 0, stream>>>(q, Wt, Xt, Bt, out);
}